// Round 1
// 5203.730 us; speedup vs baseline: 1.4731x; 1.4731x over previous
//
#include <hip/hip_runtime.h>
#include <math.h>

// Problem constants
// V=32000 S=64 T=64 B=64 E=128 EH=256 DH=256
// 3EH=768, 2EH=512, dec in = 640, pred in = 896

__device__ __forceinline__ float sigmoidf_(float x) { return 1.0f / (1.0f + expf(-x)); }

typedef __attribute__((ext_vector_type(8))) short bf16x8;
typedef __attribute__((ext_vector_type(4))) float f32x4;
typedef __attribute__((ext_vector_type(8))) unsigned short ushort8;

__device__ __forceinline__ unsigned short f2bf(float f) {
  unsigned u = __float_as_uint(f);
  unsigned r = (u + 0x7fffu + ((u >> 16) & 1u)) >> 16;
  return (unsigned short)r;
}

__global__ __launch_bounds__(256) void k_zero(float* __restrict__ p, int n4) {
  int i = blockIdx.x * 256 + threadIdx.x;
  if (i < n4) ((float4*)p)[i] = make_float4(0.f, 0.f, 0.f, 0.f);
}

// fp32 -> bf16 (RNE), 8 elements per thread, grid-stride
__global__ __launch_bounds__(256) void k_cvt_bf16(const float* __restrict__ in,
                                                  unsigned short* __restrict__ out, int n8) {
  int i = blockIdx.x * 256 + threadIdx.x;
  int stride = gridDim.x * 256;
  for (; i < n8; i += stride) {
    float4 a = ((const float4*)in)[2 * i];
    float4 b = ((const float4*)in)[2 * i + 1];
    ushort8 v;
    v[0] = f2bf(a.x); v[1] = f2bf(a.y); v[2] = f2bf(a.z); v[3] = f2bf(a.w);
    v[4] = f2bf(b.x); v[5] = f2bf(b.y); v[6] = f2bf(b.z); v[7] = f2bf(b.w);
    ((ushort8*)out)[i] = v;
  }
}

// gather rows of 128 floats: out[r] = tab[idx[r]]
__global__ __launch_bounds__(256) void k_gather(const float* __restrict__ tab,
                                                const int* __restrict__ idx,
                                                float* __restrict__ out, int rows) {
  int g = blockIdx.x * 256 + threadIdx.x;
  int row = g >> 5, c = g & 31;
  if (row < rows) {
    int tok = idx[row];
    ((float4*)(out + (size_t)row * 128))[c] = ((const float4*)(tab + (size_t)tok * 128))[c];
  }
}

// C[m,n] = sum_k A[m*lda+k]*B[n*ldb+k] + bias[n].  M%64==0 (grid.y), N%64==0, K%16==0.
__global__ __launch_bounds__(256) void k_gemm_nt(const float* __restrict__ A, int lda,
                                                 const float* __restrict__ Bm, int ldb,
                                                 const float* __restrict__ bias,
                                                 float* __restrict__ C, int ldc, int K) {
  __shared__ float As[16][68];
  __shared__ float Bs[16][68];
  int tid = threadIdx.x;
  int m0 = blockIdx.y * 64, n0 = blockIdx.x * 64;
  int lm = tid >> 2, lk = (tid & 3) * 4;
  int tm = (tid >> 4) * 4, tn = (tid & 15) * 4;
  float acc[4][4] = {};
  for (int k0 = 0; k0 < K; k0 += 16) {
    float4 av = *(const float4*)(A + (size_t)(m0 + lm) * lda + k0 + lk);
    float4 bv = *(const float4*)(Bm + (size_t)(n0 + lm) * ldb + k0 + lk);
    __syncthreads();
    As[lk + 0][lm] = av.x; As[lk + 1][lm] = av.y; As[lk + 2][lm] = av.z; As[lk + 3][lm] = av.w;
    Bs[lk + 0][lm] = bv.x; Bs[lk + 1][lm] = bv.y; Bs[lk + 2][lm] = bv.z; Bs[lk + 3][lm] = bv.w;
    __syncthreads();
#pragma unroll
    for (int k = 0; k < 16; k++) {
      float4 a4 = *(const float4*)&As[k][tm];
      float4 b4 = *(const float4*)&Bs[k][tn];
      float ar[4] = {a4.x, a4.y, a4.z, a4.w};
      float br[4] = {b4.x, b4.y, b4.z, b4.w};
#pragma unroll
      for (int i = 0; i < 4; i++)
#pragma unroll
        for (int j = 0; j < 4; j++) acc[i][j] += ar[i] * br[j];
    }
  }
  float4 bb = *(const float4*)(bias + n0 + tn);
  float br[4] = {bb.x, bb.y, bb.z, bb.w};
#pragma unroll
  for (int i = 0; i < 4; i++) {
    float* crow = C + (size_t)(m0 + tm + i) * ldc + n0 + tn;
    *(float4*)crow = make_float4(acc[i][0] + br[0], acc[i][1] + br[1],
                                 acc[i][2] + br[2], acc[i][3] + br[3]);
  }
}

// One GRU time step, both directions. 128 blocks: dir(2) x jt(8) x bg(8).
__global__ __launch_bounds__(256) void k_enc_step(
    const float* __restrict__ gi_f, const float* __restrict__ gi_b,
    const float* __restrict__ Whh_f, const float* __restrict__ Whh_b,
    const float* __restrict__ bhh_f, const float* __restrict__ bhh_b,
    const float* __restrict__ hinf, const float* __restrict__ hinb,
    float* __restrict__ houtf, float* __restrict__ houtb,
    float* __restrict__ enc_bse, int t) {
  int blk = blockIdx.x;
  int dir = blk >> 6;
  int jt = (blk >> 3) & 7, bg = blk & 7;
  const float* gi  = dir ? gi_b  : gi_f;
  const float* Whh = dir ? Whh_b : Whh_f;
  const float* bhh = dir ? bhh_b : bhh_f;
  const float* hin = dir ? hinb  : hinf;
  float* hout      = dir ? houtb : houtf;
  int s = dir ? (63 - t) : t;
  int tid = threadIdx.x;
  int b_l = tid & 7, j_l = tid >> 3;
  int b = bg * 8 + b_l, j = jt * 32 + j_l;
  __shared__ float hs[8][260];
  for (int i = tid; i < 2048; i += 256)
    hs[i >> 8][i & 255] = hin[(bg * 8 + (i >> 8)) * 256 + (i & 255)];
  __syncthreads();
  const float4* wr = (const float4*)(Whh + (size_t)j * 256);
  const float4* wz = (const float4*)(Whh + (size_t)(256 + j) * 256);
  const float4* wn = (const float4*)(Whh + (size_t)(512 + j) * 256);
  const float4* hv = (const float4*)&hs[b_l][0];
  float hr = 0.f, hz = 0.f, hn = 0.f;
#pragma unroll 8
  for (int k = 0; k < 64; k++) {
    float4 h4 = hv[k];
    float4 r4 = wr[k], z4 = wz[k], n4 = wn[k];
    hr += h4.x * r4.x + h4.y * r4.y + h4.z * r4.z + h4.w * r4.w;
    hz += h4.x * z4.x + h4.y * z4.y + h4.z * z4.z + h4.w * z4.w;
    hn += h4.x * n4.x + h4.y * n4.y + h4.z * n4.z + h4.w * n4.w;
  }
  hr += bhh[j]; hz += bhh[256 + j]; hn += bhh[512 + j];
  size_t gib = (size_t)(s * 64 + b) * 768;
  float r = sigmoidf_(gi[gib + j] + hr);
  float z = sigmoidf_(gi[gib + 256 + j] + hz);
  float n = tanhf(gi[gib + 512 + j] + r * hn);
  float h2 = (1.f - z) * n + z * hs[b_l][j];
  hout[b * 256 + j] = h2;
  enc_bse[((size_t)b * 64 + s) * 512 + dir * 256 + j] = h2;
}

// hidden = tanh([h_f,h_b] @ enc_fc_W.T + b)
__global__ __launch_bounds__(256) void k_hidden(const float* __restrict__ hf,
                                                const float* __restrict__ hb,
                                                const float* __restrict__ W,
                                                const float* __restrict__ bias,
                                                float* __restrict__ hdec) {
  int b = blockIdx.x, j = threadIdx.x;
  __shared__ float cat[512];
  cat[j] = hf[b * 256 + j];
  cat[256 + j] = hb[b * 256 + j];
  __syncthreads();
  const float4* wrow = (const float4*)(W + (size_t)j * 512);
  const float4* cv = (const float4*)cat;
  float acc = 0.f;
#pragma unroll 8
  for (int k = 0; k < 128; k++) {
    float4 w4 = wrow[k], c4 = cv[k];
    acc += w4.x * c4.x + w4.y * c4.y + w4.z * c4.z + w4.w * c4.w;
  }
  hdec[b * 256 + j] = tanhf(acc + bias[j]);
}

// Attention for one decoder step: one block per b.
__global__ __launch_bounds__(256) void k_attn(
    const float* __restrict__ hdec, const float* __restrict__ attn_W,
    const float* __restrict__ attn_v, const float* __restrict__ enc_proj,
    const float* __restrict__ enc_bse, const float* __restrict__ embd_all,
    float* __restrict__ weighted, float* __restrict__ Z, int t) {
  int b = blockIdx.x, tid = threadIdx.x;
  __shared__ float hs[256], hW[256], vs[256], sc[64];
  hs[tid] = hdec[b * 256 + tid];
  vs[tid] = attn_v[tid];
  __syncthreads();
  {
    const float4* wrow = (const float4*)(attn_W + (size_t)tid * 768);  // W_h part
    const float4* hv = (const float4*)hs;
    float acc = 0.f;
#pragma unroll 8
    for (int k = 0; k < 64; k++) {
      float4 w4 = wrow[k], h4 = hv[k];
      acc += w4.x * h4.x + w4.y * h4.y + w4.z * h4.z + w4.w * h4.w;
    }
    hW[tid] = acc;
  }
  __syncthreads();
  int w = tid >> 6, l = tid & 63;
  for (int s = w; s < 64; s += 4) {
    const float* ep = enc_proj + ((size_t)b * 64 + s) * 256;
    float p = 0.f;
#pragma unroll
    for (int i = 0; i < 4; i++) {
      int h = l + i * 64;
      p += vs[h] * tanhf(ep[h] + hW[h]);
    }
#pragma unroll
    for (int o = 32; o > 0; o >>= 1) p += __shfl_xor(p, o, 64);
    if (l == 0) sc[s] = p;
  }
  __syncthreads();
  if (tid < 64) {
    float x = sc[tid], m = x;
#pragma unroll
    for (int o = 32; o > 0; o >>= 1) m = fmaxf(m, __shfl_xor(m, o, 64));
    float e = expf(x - m), ssum = e;
#pragma unroll
    for (int o = 32; o > 0; o >>= 1) ssum += __shfl_xor(ssum, o, 64);
    sc[tid] = e / ssum;
  }
  __syncthreads();
  float a0 = 0.f, a1 = 0.f;
  const float* eb = enc_bse + (size_t)b * 64 * 512;
  for (int s = 0; s < 64; s++) {
    float a = sc[s];
    a0 += a * eb[s * 512 + tid];
    a1 += a * eb[s * 512 + 256 + tid];
  }
  size_t zr = (size_t)(t * 64 + b) * 896;
  weighted[b * 512 + tid] = a0;
  weighted[b * 512 + 256 + tid] = a1;
  Z[zr + 256 + tid] = a0;
  Z[zr + 512 + tid] = a1;
  if (tid < 128) Z[zr + 768 + tid] = embd_all[(size_t)(t * 64 + b) * 128 + tid];
}

// Decoder GRU cell step. 64 blocks: jt(8) x bg(8).
__global__ __launch_bounds__(256) void k_dec_gru(
    const float* __restrict__ weighted, const float* __restrict__ gi_emb,
    const float* __restrict__ Wih, const float* __restrict__ Whh,
    const float* __restrict__ bhh, const float* __restrict__ hin,
    float* __restrict__ hout, float* __restrict__ Z, int t) {
  int blk = blockIdx.x;
  int jt = blk & 7, bg = blk >> 3;
  int tid = threadIdx.x;
  int b_l = tid & 7, j_l = tid >> 3;
  int b = bg * 8 + b_l, j = jt * 32 + j_l;
  __shared__ float ws2[8][516];
  __shared__ float hs[8][260];
  for (int i = tid; i < 4096; i += 256)
    ws2[i >> 9][i & 511] = weighted[(bg * 8 + (i >> 9)) * 512 + (i & 511)];
  for (int i = tid; i < 2048; i += 256)
    hs[i >> 8][i & 255] = hin[(bg * 8 + (i >> 8)) * 256 + (i & 255)];
  __syncthreads();
  float gr = 0.f, gz = 0.f, gn = 0.f;
  {
    const float4* wr = (const float4*)(Wih + (size_t)j * 640 + 128);
    const float4* wz = (const float4*)(Wih + (size_t)(256 + j) * 640 + 128);
    const float4* wn = (const float4*)(Wih + (size_t)(512 + j) * 640 + 128);
    const float4* xv = (const float4*)&ws2[b_l][0];
#pragma unroll 8
    for (int k = 0; k < 128; k++) {
      float4 x4 = xv[k];
      float4 r4 = wr[k], z4 = wz[k], n4 = wn[k];
      gr += x4.x * r4.x + x4.y * r4.y + x4.z * r4.z + x4.w * r4.w;
      gz += x4.x * z4.x + x4.y * z4.y + x4.z * z4.z + x4.w * z4.w;
      gn += x4.x * n4.x + x4.y * n4.y + x4.z * n4.z + x4.w * n4.w;
    }
  }
  float hr = bhh[j], hz = bhh[256 + j], hn = bhh[512 + j];
  {
    const float4* ur = (const float4*)(Whh + (size_t)j * 256);
    const float4* uz = (const float4*)(Whh + (size_t)(256 + j) * 256);
    const float4* un = (const float4*)(Whh + (size_t)(512 + j) * 256);
    const float4* hv = (const float4*)&hs[b_l][0];
#pragma unroll 8
    for (int k = 0; k < 64; k++) {
      float4 h4 = hv[k];
      float4 r4 = ur[k], z4 = uz[k], n4 = un[k];
      hr += h4.x * r4.x + h4.y * r4.y + h4.z * r4.z + h4.w * r4.w;
      hz += h4.x * z4.x + h4.y * z4.y + h4.z * z4.z + h4.w * z4.w;
      hn += h4.x * n4.x + h4.y * n4.y + h4.z * n4.z + h4.w * n4.w;
    }
  }
  size_t gib = (size_t)(t * 64 + b) * 768;
  float r = sigmoidf_(gi_emb[gib + j] + gr + hr);
  float z = sigmoidf_(gi_emb[gib + 256 + j] + gz + hz);
  float n = tanhf(gi_emb[gib + 512 + j] + gn + r * hn);
  float h2 = (1.f - z) * n + z * hs[b_l][j];
  hout[b * 256 + j] = h2;
  Z[(size_t)(t * 64 + b) * 896 + j] = h2;
}

// Final vocab GEMM via bf16 MFMA (m97 structure: 128x128 tile, BK=64, 4 waves,
// global_load_lds width-16 staging, ds_read_b128 fragments, 16x16x32 MFMA).
// out[(m+64)*32000 + n] = Z[m,:896] . fc_W[n,:896] + fc_b[n], m < 4032.
__global__ __launch_bounds__(256) void k_fc_mfma(const unsigned short* __restrict__ Zb16,
                                                 const unsigned short* __restrict__ Wb16,
                                                 const float* __restrict__ bias,
                                                 float* __restrict__ out) {
  __shared__ unsigned short As[128 * 64];  // [row][k], k contiguous (64 per row)
  __shared__ unsigned short Bs[128 * 64];
  int tid = threadIdx.x;
  int l = tid & 63, w = tid >> 6;
  int m0 = blockIdx.y * 128, n0 = blockIdx.x * 128;
  int wr = w >> 1, wc = w & 1;  // wave sub-tile: 64x64 at (wr*64, wc*64)
  f32x4 acc[4][4] = {};

  int lrow = l >> 3;       // row within 8-row chunk
  int lk = (l & 7) * 8;    // k offset (elements) within BK

  for (int k0 = 0; k0 < 896; k0 += 64) {
    __syncthreads();  // previous iteration's LDS reads complete
#pragma unroll
    for (int i = 0; i < 4; i++) {
      int c = i * 4 + w;  // chunk 0..15 -> rows c*8 .. c*8+7
      const unsigned short* ga = Zb16 + (size_t)(m0 + c * 8 + lrow) * 896 + k0 + lk;
      const unsigned short* gb = Wb16 + (size_t)(n0 + c * 8 + lrow) * 896 + k0 + lk;
      __builtin_amdgcn_global_load_lds((const __attribute__((address_space(1))) void*)ga,
                                       (__attribute__((address_space(3))) void*)&As[c * 512],
                                       16, 0, 0);
      __builtin_amdgcn_global_load_lds((const __attribute__((address_space(1))) void*)gb,
                                       (__attribute__((address_space(3))) void*)&Bs[c * 512],
                                       16, 0, 0);
    }
    __syncthreads();  // drains vmcnt(0): tiles resident
#pragma unroll
    for (int ks = 0; ks < 2; ks++) {
      bf16x8 aF[4], bF[4];
#pragma unroll
      for (int i = 0; i < 4; i++)
        aF[i] = *(const bf16x8*)&As[(wr * 64 + i * 16 + (l & 15)) * 64 + ks * 32 + (l >> 4) * 8];
#pragma unroll
      for (int j = 0; j < 4; j++)
        bF[j] = *(const bf16x8*)&Bs[(wc * 64 + j * 16 + (l & 15)) * 64 + ks * 32 + (l >> 4) * 8];
#pragma unroll
      for (int i = 0; i < 4; i++)
#pragma unroll
        for (int j = 0; j < 4; j++)
          acc[i][j] = __builtin_amdgcn_mfma_f32_16x16x32_bf16(aF[i], bF[j], acc[i][j], 0, 0, 0);
    }
  }
  // epilogue: C/D layout col = lane&15, row = (lane>>4)*4 + r
  int cl = l & 15, rg = l >> 4;
#pragma unroll
  for (int j = 0; j < 4; j++) {
    int n = n0 + wc * 64 + j * 16 + cl;
    float bb = bias[n];
#pragma unroll
    for (int i = 0; i < 4; i++) {
      int mb = m0 + wr * 64 + i * 16 + rg * 4;
#pragma unroll
      for (int r = 0; r < 4; r++) {
        int m = mb + r;
        if (m < 4032) out[(size_t)(m + 64) * 32000 + n] = acc[i][j][r] + bb;
      }
    }
  }
}

extern "C" void kernel_launch(void* const* d_in, const int* in_sizes, int n_in,
                              void* d_out, int out_size, void* d_ws, size_t ws_size,
                              hipStream_t stream) {
  const int* src = (const int*)d_in[0];
  const int* trg = (const int*)d_in[1];
  const float* enc_emb = (const float*)d_in[2];
  const float* eWih_f  = (const float*)d_in[3];
  const float* eWhh_f  = (const float*)d_in[4];
  const float* ebih_f  = (const float*)d_in[5];
  const float* ebhh_f  = (const float*)d_in[6];
  const float* eWih_b  = (const float*)d_in[7];
  const float* eWhh_b  = (const float*)d_in[8];
  const float* ebih_b  = (const float*)d_in[9];
  const float* ebhh_b  = (const float*)d_in[10];
  const float* efc_W   = (const float*)d_in[11];
  const float* efc_b   = (const float*)d_in[12];
  const float* attn_W  = (const float*)d_in[13];
  const float* attn_b  = (const float*)d_in[14];
  const float* attn_v  = (const float*)d_in[15];
  const float* dec_emb = (const float*)d_in[16];
  const float* dWih    = (const float*)d_in[17];
  const float* dWhh    = (const float*)d_in[18];
  const float* dbih    = (const float*)d_in[19];
  const float* dbhh    = (const float*)d_in[20];
  const float* fc_W    = (const float*)d_in[21];
  const float* fc_b    = (const float*)d_in[22];
  float* out = (float*)d_out;
  float* ws = (float*)d_ws;

  size_t o = 0;
  float* emb_src  = ws + o; o += (size_t)4096 * 128;
  float* embd_all = ws + o; o += (size_t)4032 * 128;
  float* gi_f     = ws + o; o += (size_t)4096 * 768;
  float* gi_b     = ws + o; o += (size_t)4096 * 768;
  float* gi_emb   = ws + o; o += (size_t)4032 * 768;
  float* enc_bse  = ws + o; o += (size_t)4096 * 512;
  float* enc_proj = ws + o; o += (size_t)4096 * 256;
  float* h_f0 = ws + o; o += 16384;
  float* h_b0 = ws + o; o += 16384;
  float* h_f1 = ws + o; o += 16384;
  float* h_b1 = ws + o; o += 16384;
  float* h_d0 = ws + o; o += 16384;
  float* h_d1 = ws + o; o += 16384;
  float* wt   = ws + o; o += 64 * 512;
  float* Zb   = ws + o; o += (size_t)4096 * 896;
  unsigned short* Zb16 = (unsigned short*)(ws + o); o += (size_t)4096 * 896 / 2;
  unsigned short* Wb16 = (unsigned short*)(ws + o); o += (size_t)32000 * 896 / 2;

  // init: zero out row t=0, zero initial hidden states, zero Z pad rows
  k_zero<<<2000, 256, 0, stream>>>(out, 512000);                       // 64*32000 floats
  k_zero<<<32, 256, 0, stream>>>(h_f0, 8192);                          // h_f0+h_b0 contiguous
  k_zero<<<56, 256, 0, stream>>>(Zb + (size_t)4032 * 896, 14336);      // pad rows 4032..4095
  k_gather<<<512, 256, 0, stream>>>(enc_emb, src, emb_src, 4096);
  k_gather<<<504, 256, 0, stream>>>(dec_emb, trg, embd_all, 4032);

  // vocab weight fp32 -> bf16 (no dependencies; do it up front)
  k_cvt_bf16<<<2048, 256, 0, stream>>>(fc_W, Wb16, 3584000);           // 32000*896/8

  // input-side GEMMs (batched over all time steps)
  k_gemm_nt<<<dim3(12, 64), 256, 0, stream>>>(emb_src, 128, eWih_f, 128, ebih_f, gi_f, 768, 128);
  k_gemm_nt<<<dim3(12, 64), 256, 0, stream>>>(emb_src, 128, eWih_b, 128, ebih_b, gi_b, 768, 128);
  k_gemm_nt<<<dim3(12, 63), 256, 0, stream>>>(embd_all, 128, dWih, 640, dbih, gi_emb, 768, 128);

  // encoder bidirectional scan, ping-pong h buffers
  for (int t = 0; t < 64; t++) {
    const float* hif = (t & 1) ? h_f1 : h_f0;
    const float* hib = (t & 1) ? h_b1 : h_b0;
    float* hof = (t & 1) ? h_f0 : h_f1;
    float* hob = (t & 1) ? h_b0 : h_b1;
    k_enc_step<<<128, 256, 0, stream>>>(gi_f, gi_b, eWhh_f, eWhh_b, ebhh_f, ebhh_b,
                                        hif, hib, hof, hob, enc_bse, t);
  }
  // after t=63, final states are in h_f0/h_b0
  k_hidden<<<64, 256, 0, stream>>>(h_f0, h_b0, efc_W, efc_b, h_d0);
  // enc_proj = enc_bse @ W_e.T + attn_b   (W_e = attn_W[:,256:768])
  k_gemm_nt<<<dim3(4, 64), 256, 0, stream>>>(enc_bse, 512, attn_W + 256, 768, attn_b,
                                             enc_proj, 256, 512);

  // decoder scan
  for (int t = 0; t < 63; t++) {
    const float* hi = (t & 1) ? h_d1 : h_d0;
    float* ho = (t & 1) ? h_d0 : h_d1;
    k_attn<<<64, 256, 0, stream>>>(hi, attn_W, attn_v, enc_proj, enc_bse, embd_all, wt, Zb, t);
    k_dec_gru<<<64, 256, 0, stream>>>(wt, gi_emb, dWih, dWhh, dbhh, hi, ho, Zb, t);
  }

  // Z fp32 -> bf16, then batched vocab projection on the matrix cores
  k_cvt_bf16<<<1024, 256, 0, stream>>>(Zb, Zb16, 458752);              // 4096*896/8
  k_fc_mfma<<<dim3(250, 32), 256, 0, stream>>>(Zb16, Wb16, fc_b, out);
}